// Round 2
// baseline (1128.826 us; speedup 1.0000x reference)
//
#include <hip/hip_runtime.h>
#include <hip/hip_bf16.h>

#define T_STEPS 512
#define B_SZ 64
#define H_SZ 96
#define I_SZ 2048

// ---------------- GEMM: xproj0 = x @ w_ih0^T + b_ih0 ----------------
// M = 32768, K = 2048, N = 96. Tile 128(M) x 96(N) x 32(K), 256 threads,
// per-thread 8 rows x 6 cols. Vector LDS reads: 2x b128 + 3x b64 per k.
#define BM 128
#define BN 96
#define BK 32

__global__ __launch_bounds__(256) void xproj_gemm(
    const float* __restrict__ x,    // [32768, 2048]
    const float* __restrict__ w,    // [96, 2048]
    const float* __restrict__ bias, // [96]
    float* __restrict__ out)        // [32768, 96]
{
    __shared__ float xs[BK][BM + 4]; // row stride 132 floats = 528 B (16B-aligned)
    __shared__ float ws[BK][BN + 4]; // row stride 100 floats = 400 B (16B-aligned)

    const int tid = threadIdx.x;
    const int m0 = blockIdx.x * BM;
    const int tm = tid & 15;   // 16 groups * 8 rows = 128
    const int tn = tid >> 4;   // 16 groups * 6 cols = 96

    float bb[6];
#pragma unroll
    for (int c = 0; c < 6; ++c) bb[c] = bias[tn * 6 + c];

    float acc[8][6];
#pragma unroll
    for (int r = 0; r < 8; ++r)
#pragma unroll
        for (int c = 0; c < 6; ++c) acc[r][c] = 0.f;

    for (int k0 = 0; k0 < I_SZ; k0 += BK) {
        // stage x tile: 128 rows x 32 k = 1024 float4, 4 per thread
#pragma unroll
        for (int it = 0; it < 4; ++it) {
            int L = tid + it * 256;          // 0..1023
            int m = L >> 3;                  // 0..127
            int k4 = (L & 7) * 4;
            float4 v = *(const float4*)&x[(size_t)(m0 + m) * I_SZ + k0 + k4];
            xs[k4 + 0][m] = v.x; xs[k4 + 1][m] = v.y;
            xs[k4 + 2][m] = v.z; xs[k4 + 3][m] = v.w;
        }
        // stage w tile: 96 rows x 32 k = 768 float4, 3 per thread
#pragma unroll
        for (int it = 0; it < 3; ++it) {
            int L = tid + it * 256;          // 0..767
            int j = L >> 3;                  // 0..95
            int k4 = (L & 7) * 4;
            float4 v = *(const float4*)&w[(size_t)j * I_SZ + k0 + k4];
            ws[k4 + 0][j] = v.x; ws[k4 + 1][j] = v.y;
            ws[k4 + 2][j] = v.z; ws[k4 + 3][j] = v.w;
        }
        __syncthreads();

#pragma unroll
        for (int k = 0; k < BK; ++k) {
            float4 a03 = *(const float4*)&xs[k][tm * 8];
            float4 a47 = *(const float4*)&xs[k][tm * 8 + 4];
            float2 b01 = *(const float2*)&ws[k][tn * 6];
            float2 b23 = *(const float2*)&ws[k][tn * 6 + 2];
            float2 b45 = *(const float2*)&ws[k][tn * 6 + 4];
            float a[8] = {a03.x, a03.y, a03.z, a03.w, a47.x, a47.y, a47.z, a47.w};
            float b[6] = {b01.x, b01.y, b23.x, b23.y, b45.x, b45.y};
#pragma unroll
            for (int r = 0; r < 8; ++r)
#pragma unroll
                for (int c = 0; c < 6; ++c) acc[r][c] = fmaf(a[r], b[c], acc[r][c]);
        }
        __syncthreads();
    }

#pragma unroll
    for (int r = 0; r < 8; ++r) {
        float* op = &out[(size_t)(m0 + tm * 8 + r) * H_SZ + tn * 6];
        *(float2*)(op + 0) = make_float2(acc[r][0] + bb[0], acc[r][1] + bb[1]);
        *(float2*)(op + 2) = make_float2(acc[r][2] + bb[2], acc[r][3] + bb[3]);
        *(float2*)(op + 4) = make_float2(acc[r][4] + bb[4], acc[r][5] + bb[5]);
    }
}

// ---------------- Fused 3-layer pipelined recurrence + FC head ----------------
// 64 blocks (one per batch element), 512 threads = 8 waves.
//   waves 0-2: layer1, lanes paired (even: w_ih1 dot h0, odd: w_hh1 dot h1),
//              combined via shfl_xor(1). j = wave*32 + lane/2.
//   waves 3-5: layer2, same pairing (w_ih2 dot h1, w_hh2 dot h2).
//   waves 6-7: layer0, j = (wave-6)*64 + lane (j<96 active): w_hh0 dot h0 + xproj.
// Wavefront schedule: tick i -> layer0 makes h0[i], layer1 h1[i-1], layer2 h2[i-2].
// h0/h1/h2 double-buffered in LDS -> ONE barrier per tick.
// Per-thread 96-float weight row in 24 NAMED float4 registers (forced promotion).

#define W_LIST(F) F(0) F(1) F(2) F(3) F(4) F(5) F(6) F(7) F(8) F(9) F(10) F(11) \
                  F(12) F(13) F(14) F(15) F(16) F(17) F(18) F(19) F(20) F(21) F(22) F(23)

__device__ __forceinline__ float fast_tanh(float x) {
    float cx = fminf(fmaxf(x, -15.f), 15.f);
    float e = __expf(2.f * cx);
    return 1.f - 2.f / (e + 1.f);
}

__global__ __launch_bounds__(512, 2) void rnn3_fused(
    const float* __restrict__ xproj0, // [B*T, 96], includes b_ih0
    const float* __restrict__ w_hh0, const float* __restrict__ b_hh0,
    const float* __restrict__ w_ih1, const float* __restrict__ b_ih1,
    const float* __restrict__ w_hh1, const float* __restrict__ b_hh1,
    const float* __restrict__ w_ih2, const float* __restrict__ b_ih2,
    const float* __restrict__ w_hh2, const float* __restrict__ b_hh2,
    const float* __restrict__ fc_w, const float* __restrict__ fc_b,
    float* __restrict__ out)          // [B]
{
    // hls[buf][arr][96]: arr 0=h0, 1=h1, 2=h2; buf = double buffer
    __shared__ __align__(16) float hls[2 * 3 * H_SZ];
    __shared__ float red[H_SZ];

    const int t = threadIdx.x;
    const int b = blockIdx.x;
    const int wv = t >> 6;       // wave 0..7
    const int l = t & 63;
    const int even = !(l & 1);

    int j, jc, rsel, wsel;
    const float* wbase;
    if (wv < 3) {               // layer1
        j = wv * 32 + (l >> 1);
        rsel = even ? 0 : 1;    // even reads h0, odd reads h1
        wsel = 1;
        wbase = even ? w_ih1 : w_hh1;
    } else if (wv < 6) {        // layer2
        j = (wv - 3) * 32 + (l >> 1);
        rsel = even ? 1 : 2;
        wsel = 2;
        wbase = even ? w_ih2 : w_hh2;
    } else {                    // layer0
        j = (wv - 6) * 64 + l;
        rsel = 0;
        wsel = 0;
        wbase = w_hh0;
    }
    jc = j < H_SZ ? j : H_SZ - 1;
    const float* wrow = wbase + jc * H_SZ;

    // weight row -> 24 named float4 registers (unconditional, clamped)
#define DECLW(q) float4 W##q;
    W_LIST(DECLW)
#define LOADW(q) W##q = *(const float4*)&wrow[(q) * 4];
    W_LIST(LOADW)

    // combine bias
    float cb = 0.f;
    if (wv < 3)       { if (even) cb = b_ih1[jc] + b_hh1[jc]; }
    else if (wv < 6)  { if (even) cb = b_ih2[jc] + b_hh2[jc]; }
    else              { cb = b_hh0[jc]; }

    // zero both h buffers
    for (int q = t; q < 2 * 3 * H_SZ; q += 512) hls[q] = 0.f;
    __syncthreads();

    const float* xp_base = xproj0 + (size_t)b * T_STEPS * H_SZ;
    const bool is_l0 = (wv >= 6);
    float xp_cur = is_l0 ? xp_base[jc] : 0.f;

    const int rofs = rsel * H_SZ;
    const int wofs = wsel * H_SZ;

    for (int i = 0; i < T_STEPS + 2; ++i) {
        const int ci = i & 1;
        // prefetch next xproj row (overlaps with the dot)
        float xp_next = 0.f;
        if (is_l0) {
            int ii = (i + 1 < T_STEPS) ? (i + 1) : (T_STEPS - 1);
            xp_next = xp_base[(size_t)ii * H_SZ + jc];
        }

        const float4* hp = (const float4*)&hls[(ci ? 3 * H_SZ : 0) + rofs];
        float a0 = 0.f, a1 = 0.f, a2 = 0.f, a3 = 0.f;
#define DOTW(q) { float4 hv = hp[q]; \
        a0 = fmaf(W##q.x, hv.x, a0); a1 = fmaf(W##q.y, hv.y, a1); \
        a2 = fmaf(W##q.z, hv.z, a2); a3 = fmaf(W##q.w, hv.w, a3); }
        W_LIST(DOTW)
        float part = (a0 + a1) + (a2 + a3);

        // pair-combine for layers 1/2 (both lanes end up with the sum)
        float sum = part + __shfl_xor(part, 1, 64);

        // combine + write into NEXT buffer
        float* hnext = &hls[(ci ? 0 : 3 * H_SZ) + wofs];
        if (is_l0) {
            if (j < H_SZ && i < T_STEPS)
                hnext[j] = fast_tanh(xp_cur + part + cb);
        } else if (wv < 3) {
            if (even && i >= 1 && i <= T_STEPS)
                hnext[j] = fast_tanh(sum + cb);
        } else {
            if (even && i >= 2)
                hnext[j] = fast_tanh(sum + cb);
        }
        __syncthreads();

        xp_cur = xp_next;
    }

    // final h2 lives in buffer (T_STEPS+2)&1 == 0
    if (t < H_SZ) red[t] = hls[2 * H_SZ + t] * fc_w[t];
    __syncthreads();
    if (t == 0) {
        float s = 0.f;
#pragma unroll
        for (int k = 0; k < H_SZ; ++k) s += red[k];
        out[b] = s + fc_b[0];
    }
}

// ---------------- launcher ----------------
extern "C" void kernel_launch(void* const* d_in, const int* in_sizes, int n_in,
                              void* d_out, int out_size, void* d_ws, size_t ws_size,
                              hipStream_t stream) {
    const float* x     = (const float*)d_in[0];
    const float* w_ih0 = (const float*)d_in[1];
    const float* w_hh0 = (const float*)d_in[2];
    const float* b_ih0 = (const float*)d_in[3];
    const float* b_hh0 = (const float*)d_in[4];
    const float* w_ih1 = (const float*)d_in[5];
    const float* w_hh1 = (const float*)d_in[6];
    const float* b_ih1 = (const float*)d_in[7];
    const float* b_hh1 = (const float*)d_in[8];
    const float* w_ih2 = (const float*)d_in[9];
    const float* w_hh2 = (const float*)d_in[10];
    const float* b_ih2 = (const float*)d_in[11];
    const float* b_hh2 = (const float*)d_in[12];
    const float* fc_w  = (const float*)d_in[13];
    const float* fc_b  = (const float*)d_in[14];

    float* xproj = (float*)d_ws;  // 32768 * 96 floats = 12.6 MB

    const int M = B_SZ * T_STEPS; // 32768
    xproj_gemm<<<M / BM, 256, 0, stream>>>(x, w_ih0, b_ih0, xproj);
    rnn3_fused<<<B_SZ, 512, 0, stream>>>(xproj,
                                         w_hh0, b_hh0,
                                         w_ih1, b_ih1, w_hh1, b_hh1,
                                         w_ih2, b_ih2, w_hh2, b_hh2,
                                         fc_w, fc_b, (float*)d_out);
}

// Round 3
// 993.240 us; speedup vs baseline: 1.1365x; 1.1365x over previous
//
#include <hip/hip_runtime.h>
#include <hip/hip_bf16.h>

#define T_STEPS 512
#define B_SZ 64
#define H_SZ 96
#define I_SZ 2048

// ---------------- GEMM: xproj0 = x @ w_ih0^T + b_ih0 ----------------
// M = 32768, K = 2048, N = 96. Tile 64(M) x 96(N) x 32(K), 256 threads,
// per-thread 4 rows x 6 cols. Grid = 512 blocks -> 2 blocks/CU.
// Double-buffered LDS, register prefetch, one barrier per iter.
#define BM 64
#define BN 96
#define BK 32
#define XS_STRIDE 68   // 4k+4tm banks: 2-way only (free)
#define WS_STRIDE 100  // 4k+6tn banks: conflict-free

__global__ __launch_bounds__(256) void xproj_gemm(
    const float* __restrict__ x,    // [32768, 2048]
    const float* __restrict__ w,    // [96, 2048]
    const float* __restrict__ bias, // [96]
    float* __restrict__ out)        // [32768, 96]
{
    __shared__ float xs[2][BK][XS_STRIDE];
    __shared__ float ws[2][BK][WS_STRIDE];

    const int tid = threadIdx.x;
    const int m0 = blockIdx.x * BM;
    const int tm = tid & 15;   // 16 groups * 4 rows = 64
    const int tn = tid >> 4;   // 16 groups * 6 cols = 96

    // staging coordinates (fixed per thread)
    const int xm0 = tid >> 3;            // 0..31  (it adds +32)
    const int xk4 = (tid & 7) * 4;
    const int wj0 = tid >> 3;            // 0..31  (it adds +32)
    const int wk4 = xk4;

    float bb[6];
#pragma unroll
    for (int c = 0; c < 6; ++c) bb[c] = bias[tn * 6 + c];

    float acc[4][6];
#pragma unroll
    for (int r = 0; r < 4; ++r)
#pragma unroll
        for (int c = 0; c < 6; ++c) acc[r][c] = 0.f;

    float4 xr[2], wr[3];

    // prologue: load + store tile 0
#pragma unroll
    for (int it = 0; it < 2; ++it)
        xr[it] = *(const float4*)&x[(size_t)(m0 + xm0 + it * 32) * I_SZ + xk4];
#pragma unroll
    for (int it = 0; it < 3; ++it)
        wr[it] = *(const float4*)&w[(size_t)(wj0 + it * 32) * I_SZ + wk4];
#pragma unroll
    for (int it = 0; it < 2; ++it) {
        int m = xm0 + it * 32;
        xs[0][xk4 + 0][m] = xr[it].x; xs[0][xk4 + 1][m] = xr[it].y;
        xs[0][xk4 + 2][m] = xr[it].z; xs[0][xk4 + 3][m] = xr[it].w;
    }
#pragma unroll
    for (int it = 0; it < 3; ++it) {
        int j = wj0 + it * 32;
        ws[0][wk4 + 0][j] = wr[it].x; ws[0][wk4 + 1][j] = wr[it].y;
        ws[0][wk4 + 2][j] = wr[it].z; ws[0][wk4 + 3][j] = wr[it].w;
    }
    __syncthreads();

    for (int itn = 0; itn < I_SZ / BK; ++itn) {
        const int buf = itn & 1;
        const int k0n = (itn + 1) * BK;
        // prefetch next tile into registers (latency hidden by compute)
        if (itn < I_SZ / BK - 1) {
#pragma unroll
            for (int it = 0; it < 2; ++it)
                xr[it] = *(const float4*)&x[(size_t)(m0 + xm0 + it * 32) * I_SZ + k0n + xk4];
#pragma unroll
            for (int it = 0; it < 3; ++it)
                wr[it] = *(const float4*)&w[(size_t)(wj0 + it * 32) * I_SZ + k0n + wk4];
        }

#pragma unroll
        for (int k = 0; k < BK; ++k) {
            float4 a = *(const float4*)&xs[buf][k][tm * 4];
            float2 b01 = *(const float2*)&ws[buf][k][tn * 6];
            float2 b23 = *(const float2*)&ws[buf][k][tn * 6 + 2];
            float2 b45 = *(const float2*)&ws[buf][k][tn * 6 + 4];
            float av[4] = {a.x, a.y, a.z, a.w};
            float bv[6] = {b01.x, b01.y, b23.x, b23.y, b45.x, b45.y};
#pragma unroll
            for (int r = 0; r < 4; ++r)
#pragma unroll
                for (int c = 0; c < 6; ++c) acc[r][c] = fmaf(av[r], bv[c], acc[r][c]);
        }

        if (itn < I_SZ / BK - 1) {
            const int nb = buf ^ 1;
#pragma unroll
            for (int it = 0; it < 2; ++it) {
                int m = xm0 + it * 32;
                xs[nb][xk4 + 0][m] = xr[it].x; xs[nb][xk4 + 1][m] = xr[it].y;
                xs[nb][xk4 + 2][m] = xr[it].z; xs[nb][xk4 + 3][m] = xr[it].w;
            }
#pragma unroll
            for (int it = 0; it < 3; ++it) {
                int j = wj0 + it * 32;
                ws[nb][wk4 + 0][j] = wr[it].x; ws[nb][wk4 + 1][j] = wr[it].y;
                ws[nb][wk4 + 2][j] = wr[it].z; ws[nb][wk4 + 3][j] = wr[it].w;
            }
        }
        __syncthreads();
    }

#pragma unroll
    for (int r = 0; r < 4; ++r) {
        float* op = &out[(size_t)(m0 + tm * 4 + r) * H_SZ + tn * 6];
        *(float2*)(op + 0) = make_float2(acc[r][0] + bb[0], acc[r][1] + bb[1]);
        *(float2*)(op + 2) = make_float2(acc[r][2] + bb[2], acc[r][3] + bb[3]);
        *(float2*)(op + 4) = make_float2(acc[r][4] + bb[4], acc[r][5] + bb[5]);
    }
}

// ---------------- Fused 3-layer pipelined recurrence + FC head ----------------
// 64 blocks (one per batch), 1024 threads = 16 waves.
//   t in [0,384):   layer1. j = t>>2, sub = t&3 -> (ih/hh) x (lo/hi 48-half).
//   t in [384,768): layer2, same quad structure.
//   t in [768,960): layer0. j = (t-768)>>1, sub = t&1 -> hh (lo/hi half).
//   t in [960,1024): idle.
// Each thread: 48-float weight half-row in 12 NAMED float4 regs (fits 128 VGPR
// budget for 1024-thread blocks -> no spill). Quad/pair combine via shfl_xor.
// xproj[b] preloaded into LDS in 256-tick chunks -> no per-tick global loads.
// Wavefront schedule: tick i -> layer0 h0[i], layer1 h1[i-1], layer2 h2[i-2].

#define W12_LIST(F) F(0) F(1) F(2) F(3) F(4) F(5) F(6) F(7) F(8) F(9) F(10) F(11)

__device__ __forceinline__ float fast_tanh(float x) {
    float cx = fminf(fmaxf(x, -15.f), 15.f);
    float e = __expf(2.f * cx);
    return 1.f - 2.f / (e + 1.f);
}

#define CHUNK 256

__global__ __launch_bounds__(1024) void rnn3_fused(
    const float* __restrict__ xproj0, // [B*T, 96], includes b_ih0
    const float* __restrict__ w_hh0, const float* __restrict__ b_hh0,
    const float* __restrict__ w_ih1, const float* __restrict__ b_ih1,
    const float* __restrict__ w_hh1, const float* __restrict__ b_hh1,
    const float* __restrict__ w_ih2, const float* __restrict__ b_ih2,
    const float* __restrict__ w_hh2, const float* __restrict__ b_hh2,
    const float* __restrict__ fc_w, const float* __restrict__ fc_b,
    float* __restrict__ out)          // [B]
{
    __shared__ __align__(16) float xp_ch[CHUNK * H_SZ];   // 96 KB
    __shared__ __align__(16) float hls[2 * 3 * H_SZ];     // double-buffered h0/h1/h2
    __shared__ float red[H_SZ];

    const int t = threadIdx.x;
    const int b = blockIdx.x;

    int j = 0, sub = 0, rofs = 0, wsel = 0, layer = 3;
    const float* wrow = w_hh0;
    if (t < 384) {                      // layer1
        j = t >> 2; sub = t & 3; layer = 1;
        wrow = ((sub < 2) ? w_ih1 : w_hh1) + j * H_SZ + (sub & 1) * 48;
        rofs = ((sub < 2) ? 0 : 1) * H_SZ + (sub & 1) * 48;
        wsel = 1;
    } else if (t < 768) {               // layer2
        int u = t - 384; j = u >> 2; sub = u & 3; layer = 2;
        wrow = ((sub < 2) ? w_ih2 : w_hh2) + j * H_SZ + (sub & 1) * 48;
        rofs = ((sub < 2) ? 1 : 2) * H_SZ + (sub & 1) * 48;
        wsel = 2;
    } else if (t < 960) {               // layer0
        int u = t - 768; j = u >> 1; sub = u & 1; layer = 0;
        wrow = w_hh0 + j * H_SZ + sub * 48;
        rofs = sub * 48;
        wsel = 0;
    }

    // 48-float weight half-row -> 12 named float4 regs (unconditional loads)
#define DECLW(q) float4 W##q = *(const float4*)&wrow[(q) * 4];
    W12_LIST(DECLW)

    float cb = 0.f;
    if (sub == 0) {
        if (layer == 0)      cb = b_hh0[j];
        else if (layer == 1) cb = b_ih1[j] + b_hh1[j];
        else if (layer == 2) cb = b_ih2[j] + b_hh2[j];
    }

    for (int q = t; q < 2 * 3 * H_SZ; q += 1024) hls[q] = 0.f;

    const float* xp_base = xproj0 + (size_t)b * T_STEPS * H_SZ;

    for (int i = 0; i < T_STEPS + 2; ++i) {
        if ((i & (CHUNK - 1)) == 0 && i < T_STEPS) {
            // stage rows [i, i+CHUNK) : 24576 floats = 6144 float4, 6/thread
            const float4* src = (const float4*)(xp_base + (size_t)i * H_SZ);
            float4* dst = (float4*)xp_ch;
#pragma unroll
            for (int q = 0; q < 6; ++q) dst[t + q * 1024] = src[t + q * 1024];
        }
        __syncthreads();   // tick barrier + staging visibility

        // xp for layer0 combine lanes (LDS, latency hidden under the dot)
        float xpv = 0.f;
        if (layer == 0 && sub == 0) xpv = xp_ch[(i & (CHUNK - 1)) * H_SZ + j];

        const float4* hp = (const float4*)&hls[(i & 1) * (3 * H_SZ) + rofs];
        float a0 = 0.f, a1 = 0.f, a2 = 0.f, a3 = 0.f;
#define DOTW(q) { float4 hv = hp[q]; \
        a0 = fmaf(W##q.x, hv.x, a0); a1 = fmaf(W##q.y, hv.y, a1); \
        a2 = fmaf(W##q.z, hv.z, a2); a3 = fmaf(W##q.w, hv.w, a3); }
        W12_LIST(DOTW)
        float part = (a0 + a1) + (a2 + a3);

        float s = part + __shfl_xor(part, 1, 64);
        if (t < 768) s += __shfl_xor(s, 2, 64);   // wave-uniform branch

        float* hn = &hls[((i & 1) ^ 1) * (3 * H_SZ) + wsel * H_SZ];
        if (sub == 0) {
            if (layer == 0)      { if (i < T_STEPS)            hn[j] = fast_tanh(xpv + s + cb); }
            else if (layer == 1) { if (i >= 1 && i <= T_STEPS) hn[j] = fast_tanh(s + cb); }
            else if (layer == 2) { if (i >= 2)                 hn[j] = fast_tanh(s + cb); }
        }
        __syncthreads();
    }

    // final h2 is in buffer ((T_STEPS+2) & 1) == 0
    if (t < H_SZ) red[t] = hls[2 * H_SZ + t] * fc_w[t];
    __syncthreads();
    if (t == 0) {
        float sm = 0.f;
#pragma unroll
        for (int k = 0; k < H_SZ; ++k) sm += red[k];
        out[b] = sm + fc_b[0];
    }
}

// ---------------- launcher ----------------
extern "C" void kernel_launch(void* const* d_in, const int* in_sizes, int n_in,
                              void* d_out, int out_size, void* d_ws, size_t ws_size,
                              hipStream_t stream) {
    const float* x     = (const float*)d_in[0];
    const float* w_ih0 = (const float*)d_in[1];
    const float* w_hh0 = (const float*)d_in[2];
    const float* b_ih0 = (const float*)d_in[3];
    const float* b_hh0 = (const float*)d_in[4];
    const float* w_ih1 = (const float*)d_in[5];
    const float* w_hh1 = (const float*)d_in[6];
    const float* b_ih1 = (const float*)d_in[7];
    const float* b_hh1 = (const float*)d_in[8];
    const float* w_ih2 = (const float*)d_in[9];
    const float* w_hh2 = (const float*)d_in[10];
    const float* b_ih2 = (const float*)d_in[11];
    const float* b_hh2 = (const float*)d_in[12];
    const float* fc_w  = (const float*)d_in[13];
    const float* fc_b  = (const float*)d_in[14];

    float* xproj = (float*)d_ws;  // 32768 * 96 floats = 12.6 MB

    const int M = B_SZ * T_STEPS; // 32768
    xproj_gemm<<<M / BM, 256, 0, stream>>>(x, w_ih0, b_ih0, xproj);
    rnn3_fused<<<B_SZ, 1024, 0, stream>>>(xproj,
                                          w_hh0, b_hh0,
                                          w_ih1, b_ih1, w_hh1, b_hh1,
                                          w_ih2, b_ih2, w_hh2, b_hh2,
                                          fc_w, fc_b, (float*)d_out);
}

// Round 4
// 838.408 us; speedup vs baseline: 1.3464x; 1.1847x over previous
//
#include <hip/hip_runtime.h>
#include <hip/hip_bf16.h>

#define T_STEPS 512
#define B_SZ 64
#define H_SZ 96
#define I_SZ 2048

// ---------------- GEMM: xproj0 = x @ w_ih0^T + b_ih0 ----------------
// M=32768, K=2048, N=96. Tile 64(M) x 96(N) x 32(K), 256 threads, grid 512
// (2 blocks/CU). Async global_load_lds(16B) staging into XOR-swizzled
// row-major tiles (no transpose stores, conflict-free reads), double-buffered
// m97-style (issue next tile's loads, compute current, barrier). Inner loop
// steps 4 k's at a time: A/B fragments read as b128 along k.
#define BM 64
#define BN 96
#define BK 32

typedef const __attribute__((address_space(1))) void g_void;
typedef __attribute__((address_space(3))) void l_void;

__device__ __forceinline__ void stage_tile(const float* __restrict__ x,
                                           const float* __restrict__ w,
                                           float* xsf, float* wsf,
                                           int buf, int m0, int k0, int tid) {
    // x tile: 64 rows x 32 k = 512 16B-chunks, 2 per thread
#pragma unroll
    for (int it = 0; it < 2; ++it) {
        int L = tid + it * 256;              // 0..511
        int m = L >> 3;                      // 0..63
        int c = (L & 7) ^ ((L >> 5) & 7);    // swizzled k-chunk
        const float* g = &x[(size_t)(m0 + m) * I_SZ + k0 + c * 4];
        __builtin_amdgcn_global_load_lds((g_void*)g,
            (l_void*)(xsf + buf * (BM * BK) + L * 4), 16, 0, 0);
    }
    // w tile: 96 rows x 32 k = 768 chunks, 3 per thread
#pragma unroll
    for (int it = 0; it < 3; ++it) {
        int L = tid + it * 256;              // 0..767
        int j = L >> 3;                      // 0..95
        int c = (L & 7) ^ ((L >> 5) & 7);
        const float* g = &w[(size_t)j * I_SZ + k0 + c * 4];
        __builtin_amdgcn_global_load_lds((g_void*)g,
            (l_void*)(wsf + buf * (BN * BK) + L * 4), 16, 0, 0);
    }
}

__global__ __launch_bounds__(256) void xproj_gemm(
    const float* __restrict__ x,    // [32768, 2048]
    const float* __restrict__ w,    // [96, 2048]
    const float* __restrict__ bias, // [96]
    float* __restrict__ out)        // [32768, 96]
{
    __shared__ __align__(16) float xsf[2 * BM * BK];  // [buf][m][chunk-swizzled]
    __shared__ __align__(16) float wsf[2 * BN * BK];

    const int tid = threadIdx.x;
    const int m0 = blockIdx.x * BM;
    const int tm = tid & 15;   // 16 groups * 4 rows
    const int tn = tid >> 4;   // 16 groups * 6 cols

    float bb[6];
#pragma unroll
    for (int c = 0; c < 6; ++c) bb[c] = bias[tn * 6 + c];

    // fragment read offsets (float4 indices) + per-row swizzle keys
    int aoff[4], boff[6], sb[6];
    const int sa = tm & 7;
#pragma unroll
    for (int r = 0; r < 4; ++r) aoff[r] = (tm * 4 + r) * 8;
#pragma unroll
    for (int c = 0; c < 6; ++c) {
        int j = tn * 6 + c;
        boff[c] = j * 8;
        sb[c] = (j >> 2) & 7;
    }

    float acc[4][6];
#pragma unroll
    for (int r = 0; r < 4; ++r)
#pragma unroll
        for (int c = 0; c < 6; ++c) acc[r][c] = 0.f;

    stage_tile(x, w, xsf, wsf, 0, m0, 0, tid);
    __syncthreads();

    for (int tile = 0; tile < I_SZ / BK; ++tile) {
        const int buf = tile & 1;
        if (tile < I_SZ / BK - 1)
            stage_tile(x, w, xsf, wsf, buf ^ 1, m0, (tile + 1) * BK, tid);

        const float4* xsb = (const float4*)(xsf + buf * (BM * BK));
        const float4* wsb = (const float4*)(wsf + buf * (BN * BK));
#pragma unroll
        for (int cc = 0; cc < 8; ++cc) {   // 8 chunks of 4 k
            float av[4][4], bv[6][4];
#pragma unroll
            for (int r = 0; r < 4; ++r)
                *(float4*)av[r] = xsb[aoff[r] + (cc ^ sa)];
#pragma unroll
            for (int c = 0; c < 6; ++c)
                *(float4*)bv[c] = wsb[boff[c] + (cc ^ sb[c])];
#pragma unroll
            for (int kk = 0; kk < 4; ++kk)
#pragma unroll
                for (int r = 0; r < 4; ++r)
#pragma unroll
                    for (int c = 0; c < 6; ++c)
                        acc[r][c] = fmaf(av[r][kk], bv[c][kk], acc[r][c]);
        }
        __syncthreads();
    }

#pragma unroll
    for (int r = 0; r < 4; ++r) {
        float* op = &out[(size_t)(m0 + tm * 4 + r) * H_SZ + tn * 6];
        *(float2*)(op + 0) = make_float2(acc[r][0] + bb[0], acc[r][1] + bb[1]);
        *(float2*)(op + 2) = make_float2(acc[r][2] + bb[2], acc[r][3] + bb[3]);
        *(float2*)(op + 4) = make_float2(acc[r][4] + bb[4], acc[r][5] + bb[5]);
    }
}

// ---------------- Fused 3-layer pipelined recurrence + FC head ----------------
// 64 blocks, 512 threads = 8 waves.
//   waves 0-2: layer1. lanes[0:32)=w_ih1 (reads h0), lanes[32:64)=w_hh1 (h1).
//   waves 3-5: layer2. ih2 (h1) / hh2 (h2).
//   waves 6-7: layer0. w_hh0 (h0); wave7 upper half idle (j>=96).
// Within a 32-half: quad q = 8 quads, lanes sub=0..3. Thread covers 4 j
// (j0=base+q*4) x 24 k (k0=sub*24): 96 weights in 24 NAMED float4 regs.
// Combine: 3-shfl quad butterfly (lane sub ends owning j0+sub over all 96 k),
// then shfl_xor(32) adds the partner matrix's dot. ONE barrier per tick.
// xproj staged into LDS in 256-tick chunks.

#define WQ_LIST(F) \
    F(0,0) F(0,1) F(0,2) F(0,3) F(0,4) F(0,5) \
    F(1,0) F(1,1) F(1,2) F(1,3) F(1,4) F(1,5) \
    F(2,0) F(2,1) F(2,2) F(2,3) F(2,4) F(2,5) \
    F(3,0) F(3,1) F(3,2) F(3,3) F(3,4) F(3,5)

__device__ __forceinline__ float fast_tanh(float x) {
    float cx = fminf(fmaxf(x, -15.f), 15.f);
    float e = __expf(2.f * cx);
    return 1.f - 2.f / (e + 1.f);
}

#define CHUNK 256

__global__ __launch_bounds__(512, 2) void rnn3_fused(
    const float* __restrict__ xproj0, // [B*T, 96], includes b_ih0
    const float* __restrict__ w_hh0, const float* __restrict__ b_hh0,
    const float* __restrict__ w_ih1, const float* __restrict__ b_ih1,
    const float* __restrict__ w_hh1, const float* __restrict__ b_hh1,
    const float* __restrict__ w_ih2, const float* __restrict__ b_ih2,
    const float* __restrict__ w_hh2, const float* __restrict__ b_hh2,
    const float* __restrict__ fc_w, const float* __restrict__ fc_b,
    float* __restrict__ out)          // [B]
{
    __shared__ __align__(16) float xp_ch[CHUNK * H_SZ];   // 96 KB
    __shared__ __align__(16) float hls[2 * 3 * H_SZ];     // dbuf h0/h1/h2
    __shared__ float red[H_SZ];

    const int t = threadIdx.x;
    const int b = blockIdx.x;
    const int wv = t >> 6;
    const int l = t & 63;

    int half, q, sub, j0, in_sel, out_sel, layer;
    const float* mat;
    if (wv < 6) {
        half = l >> 5; int lq = l & 31; q = lq >> 2; sub = lq & 3;
        if (wv < 3) { layer = 1; j0 = wv * 32 + q * 4;
                      mat = half ? w_hh1 : w_ih1; in_sel = half ? 1 : 0; out_sel = 1; }
        else        { layer = 2; j0 = (wv - 3) * 32 + q * 4;
                      mat = half ? w_hh2 : w_ih2; in_sel = half ? 2 : 1; out_sel = 2; }
    } else {
        half = 0; q = l >> 2; sub = l & 3; layer = 0;
        j0 = (wv - 6) * 64 + q * 4;
        mat = w_hh0; in_sel = 0; out_sel = 0;
    }
    const bool jvalid = (j0 < H_SZ);
    const int j0c = jvalid ? j0 : H_SZ - 4;
    const int jme = j0c + sub;                // final owned output index
    const float* wrb = mat + j0c * H_SZ + sub * 24;

    // 4 j x 24 k weights -> 24 named float4 (unconditional loads)
#define DECLW(r, c) float4 W##r##_##c = *(const float4*)(wrb + (r) * H_SZ + (c) * 4);
    WQ_LIST(DECLW)

    float cb;
    if (layer == 0)      cb = b_hh0[jme];
    else if (layer == 1) cb = b_ih1[jme] + b_hh1[jme];
    else                 cb = b_ih2[jme] + b_hh2[jme];

    for (int k = t; k < 2 * 3 * H_SZ; k += 512) hls[k] = 0.f;
    __syncthreads();

    const float* xp_base = xproj0 + (size_t)b * T_STEPS * H_SZ;

    for (int i = 0; i < T_STEPS + 2; ++i) {
        if ((i & (CHUNK - 1)) == 0 && i < T_STEPS) {
            const float4* src = (const float4*)(xp_base + (size_t)i * H_SZ);
            float4* dst = (float4*)xp_ch;
#pragma unroll
            for (int qq = 0; qq < 12; ++qq) dst[t + qq * 512] = src[t + qq * 512];
            __syncthreads();
        }
        const int buf = i & 1;

        const float4* hp = (const float4*)&hls[buf * (3 * H_SZ) + in_sel * H_SZ + sub * 24];
        float4 hv0 = hp[0], hv1 = hp[1], hv2 = hp[2], hv3 = hp[3], hv4 = hp[4], hv5 = hp[5];

        float xpv = 0.f;
        if (layer == 0) xpv = xp_ch[(i & (CHUNK - 1)) * H_SZ + jme];

        float a0 = 0.f, a1 = 0.f, a2 = 0.f, a3 = 0.f;
#define DOTQ(r, c) { a##r = fmaf(W##r##_##c.x, hv##c.x, a##r); \
                     a##r = fmaf(W##r##_##c.y, hv##c.y, a##r); \
                     a##r = fmaf(W##r##_##c.z, hv##c.z, a##r); \
                     a##r = fmaf(W##r##_##c.w, hv##c.w, a##r); }
        WQ_LIST(DOTQ)

        // quad butterfly: lane sub ends owning j0+sub summed over all 96 k
        float m0 = (sub & 1) ? a0 : a1;
        float m1 = (sub & 1) ? a2 : a3;
        float x0 = __shfl_xor(m0, 1, 64);
        float x1 = __shfl_xor(m1, 1, 64);
        float u0 = ((sub & 1) ? a1 : a0) + x0;
        float u1 = ((sub & 1) ? a3 : a2) + x1;
        float m2 = (sub & 2) ? u0 : u1;
        float x2 = __shfl_xor(m2, 2, 64);
        float fin = ((sub & 2) ? u1 : u0) + x2;

        // cross-matrix combine (ih + hh) for layers 1/2
        float fin2 = fin + __shfl_xor(fin, 32, 64);

        float* hn = &hls[(buf ^ 1) * (3 * H_SZ) + out_sel * H_SZ];
        if (layer == 0) {
            if (jvalid && i < T_STEPS) hn[jme] = fast_tanh(fin + xpv + cb);
        } else if (half == 0) {
            bool ok = (layer == 1) ? (i >= 1 && i <= T_STEPS) : (i >= 2);
            if (ok) hn[jme] = fast_tanh(fin2 + cb);
        }
        __syncthreads();
    }

    // final h2 is in buffer ((T_STEPS+2) & 1) == 0
    if (t < H_SZ) red[t] = hls[2 * H_SZ + t] * fc_w[t];
    __syncthreads();
    if (t == 0) {
        float sm = 0.f;
#pragma unroll
        for (int k = 0; k < H_SZ; ++k) sm += red[k];
        out[b] = sm + fc_b[0];
    }
}

// ---------------- launcher ----------------
extern "C" void kernel_launch(void* const* d_in, const int* in_sizes, int n_in,
                              void* d_out, int out_size, void* d_ws, size_t ws_size,
                              hipStream_t stream) {
    const float* x     = (const float*)d_in[0];
    const float* w_ih0 = (const float*)d_in[1];
    const float* w_hh0 = (const float*)d_in[2];
    const float* b_ih0 = (const float*)d_in[3];
    const float* b_hh0 = (const float*)d_in[4];
    const float* w_ih1 = (const float*)d_in[5];
    const float* w_hh1 = (const float*)d_in[6];
    const float* b_ih1 = (const float*)d_in[7];
    const float* b_hh1 = (const float*)d_in[8];
    const float* w_ih2 = (const float*)d_in[9];
    const float* w_hh2 = (const float*)d_in[10];
    const float* b_ih2 = (const float*)d_in[11];
    const float* b_hh2 = (const float*)d_in[12];
    const float* fc_w  = (const float*)d_in[13];
    const float* fc_b  = (const float*)d_in[14];

    float* xproj = (float*)d_ws;  // 32768 * 96 floats = 12.6 MB

    const int M = B_SZ * T_STEPS; // 32768
    xproj_gemm<<<M / BM, 256, 0, stream>>>(x, w_ih0, b_ih0, xproj);
    rnn3_fused<<<B_SZ, 512, 0, stream>>>(xproj,
                                         w_hh0, b_hh0,
                                         w_ih1, b_ih1, w_hh1, b_hh1,
                                         w_ih2, b_ih2, w_hh2, b_hh2,
                                         fc_w, fc_b, (float*)d_out);
}